// Round 14
// baseline (185.110 us; speedup 1.0000x reference)
//
#include <hip/hip_runtime.h>
#include <hip/hip_bf16.h>

typedef __attribute__((ext_vector_type(8))) short short8;
typedef __attribute__((ext_vector_type(4))) float f32x4;
typedef __attribute__((ext_vector_type(2))) unsigned int uint2v;
typedef __attribute__((ext_vector_type(4))) unsigned int uint4v;
typedef unsigned int u32;

#define QSCALE 0.1803368801111204f  // 0.125 * log2(e), folded into Q

__device__ inline ushort f2bf(float f) {
    unsigned int i = __builtin_bit_cast(unsigned int, f);
    unsigned int r = (i + 0x7FFFu + ((i >> 16) & 1u)) >> 16;  // RNE
    return (ushort)r;
}
// hardware v_cvt_pk_bf16_f32 (memcpy dodges non-trivially-copyable bit_cast)
__device__ inline u32 pack_bf16(float a, float b) {
    float2 f2; f2.x = a; f2.y = b;
    __hip_bfloat162 h = __float22bfloat162_rn(f2);
    u32 r; __builtin_memcpy(&r, &h, 4);
    return r;
}

// async 16B global->LDS (lane i lands at wave-uniform base + i*16)
__device__ __forceinline__ void gload_lds16(const ushort* g, ushort* l) {
    __builtin_amdgcn_global_load_lds(
        (const __attribute__((address_space(1))) u32*)g,
        (__attribute__((address_space(3))) u32*)l, 16, 0, 0);
}

// -------- convert: x fp32 -> bf16, 8 elems/thread (per-batch fallback) -------
__global__ __launch_bounds__(256) void convert_f32_bf16(
    const float* __restrict__ in, ushort* __restrict__ outp, int n8)
{
    int idx = blockIdx.x * 256 + threadIdx.x;
    if (idx >= n8) return;
    const float4 u0 = *(const float4*)&in[(size_t)idx * 8];
    const float4 u1 = *(const float4*)&in[(size_t)idx * 8 + 4];
    uint2v a, b;
    a.x = pack_bf16(u0.x, u0.y); a.y = pack_bf16(u0.z, u0.w);
    b.x = pack_bf16(u1.x, u1.y); b.y = pack_bf16(u1.z, u1.w);
    *(uint2v*)&outp[(size_t)idx * 8] = a;
    *(uint2v*)&outp[(size_t)idx * 8 + 4] = b;
}

// -------- transpose+convert: W[K][N] (fp32) -> Wt[N][K] (bf16) (fallback) ----
__global__ __launch_bounds__(256) void transpose_f32_bf16(
    const float* __restrict__ W, ushort* __restrict__ Wt, int K, int N)
{
    __shared__ float tile[32][33];
    const int n0 = blockIdx.x * 32;
    const int k0 = blockIdx.y * 32;
    const int tx = threadIdx.x & 31;
    const int ty = threadIdx.x >> 5;
    for (int i = ty; i < 32; i += 8)
        tile[i][tx] = W[(size_t)(k0 + i) * N + n0 + tx];
    __syncthreads();
    for (int i = ty; i < 32; i += 8)
        Wt[(size_t)(n0 + i) * K + k0 + tx] = f2bf(tile[tx][i]);
}

// -------- fused prep: convert(x) + transpose(qkv_w) + transpose(proj_w) ------
// blocks [0,3072): convert; [3072,4800): W1 72x24; [4800,5376): W2 24x24.
__global__ __launch_bounds__(256) void prep_kernel(
    const float* __restrict__ x, ushort* __restrict__ xb,
    const float* __restrict__ qkv_w, ushort* __restrict__ Wt1,
    const float* __restrict__ proj_w, ushort* __restrict__ Wt2)
{
    __shared__ float tile[32][33];
    const int blk = blockIdx.x;
    if (blk < 3072) {
        const int idx = blk * 256 + threadIdx.x;
        const float4 u0 = *(const float4*)&x[(size_t)idx * 8];
        const float4 u1 = *(const float4*)&x[(size_t)idx * 8 + 4];
        uint2v a, b;
        a.x = pack_bf16(u0.x, u0.y); a.y = pack_bf16(u0.z, u0.w);
        b.x = pack_bf16(u1.x, u1.y); b.y = pack_bf16(u1.z, u1.w);
        *(uint2v*)&xb[(size_t)idx * 8] = a;
        *(uint2v*)&xb[(size_t)idx * 8 + 4] = b;
        return;
    }
    const float* W;  ushort* Wt;  int K, N, n0, k0;
    if (blk < 4800) {
        const int i = blk - 3072;
        W = qkv_w; Wt = Wt1; K = 768; N = 2304;
        n0 = (i % 72) * 32; k0 = (i / 72) * 32;
    } else {
        const int i = blk - 4800;
        W = proj_w; Wt = Wt2; K = 768; N = 768;
        n0 = (i % 24) * 32; k0 = (i / 24) * 32;
    }
    const int tx = threadIdx.x & 31;
    const int ty = threadIdx.x >> 5;
    for (int i = ty; i < 32; i += 8)
        tile[i][tx] = W[(size_t)(k0 + i) * N + n0 + tx];
    __syncthreads();
    for (int i = ty; i < 32; i += 8)
        Wt[(size_t)(n0 + i) * K + k0 + tx] = f2bf(tile[tx][i]);
}

// ------ GEMM (128x128 tile, 8 WAVES, BK=64, dbuf, counted-vmcnt) ------
// R14: + counted LGKMCNT split (T4 idiom on the LDS side): issue s=0 reads
// (6), then s=1 reads (6), wait lgkmcnt(6) -> s=0 MFMAs run UNDER s=1 read
// latency -> lgkmcnt(0) -> barrier (buf-reuse safety unchanged) -> stage ->
// s=1 MFMAs. DS ops retire in order; sched_barrier(0) pins group order.
// QKV_MODE: col<768 (Q) -> *QSCALE ->C; col<1536 (K) -> C; else (V) -> Vt
template <bool OUT_FP32, bool QKV_MODE>
__global__ __launch_bounds__(512) void gemm_bt(
    const ushort* __restrict__ A, const ushort* __restrict__ Bt,
    const float* __restrict__ bias, void* __restrict__ C,
    ushort* __restrict__ Vt, int M, int N, int K, int ldc)
{
    __shared__ __attribute__((aligned(16))) ushort As[2][128][64];
    __shared__ __attribute__((aligned(16))) ushort Bs[2][128][64];
    const int tid  = threadIdx.x;
    const int lane = tid & 63;
    const int w    = tid >> 6;            // 0..7
    const int wm   = (w >> 2) * 64;       // wave-row: 2 groups of 64 rows
    const int wn   = (w & 3) * 32;        // wave-col: 4 groups of 32 cols
    const int g    = lane >> 4;
    const int t    = lane & 15;
    const int m0   = blockIdx.x * 128;
    const int n0   = blockIdx.y * 128;

    const int lr = lane >> 3;       // 0..7
    const int pc = lane & 7;        // 0..7
    const int xorc = t & 7;

    f32x4 acc[4][2];
#pragma unroll
    for (int i = 0; i < 4; i++)
#pragma unroll
        for (int j = 0; j < 2; j++) acc[i][j] = {0.f, 0.f, 0.f, 0.f};

    const int nsteps = K >> 6;

    auto stage = [&](int buf, int kt) {   // 4 gload_lds per wave (A:2, B:2)
        const int k0 = kt * 64;
#pragma unroll
        for (int p = 0; p < 2; p++) {
            const int row = p * 64 + w * 8 + lr;            // 0..127
            const int gc  = pc ^ (row & 7);
            gload_lds16(&A[(size_t)(m0 + row) * K + k0 + gc * 8], &As[buf][p * 64 + w * 8][0]);
            gload_lds16(&Bt[(size_t)(n0 + row) * K + k0 + gc * 8], &Bs[buf][p * 64 + w * 8][0]);
        }
    };

    // prologue: 2-deep prefetch; wait only tile 0 (4 of 8 outstanding)
    stage(0, 0);
    stage(1, 1);
    asm volatile("s_waitcnt vmcnt(4)" ::: "memory");
    __builtin_amdgcn_sched_barrier(0);
    __builtin_amdgcn_s_barrier();
    __builtin_amdgcn_sched_barrier(0);

    for (int kt = 0; kt < nsteps; kt++) {
        const int cur = kt & 1;
        short8 a[2][4], b[2][2];
        // s=0 read group (6 ds_read_b128)
        {
            const int ca = (g ^ xorc) * 8;
#pragma unroll
            for (int i = 0; i < 4; i++)
                a[0][i] = *(const short8*)&As[cur][wm + i * 16 + t][ca];
#pragma unroll
            for (int j = 0; j < 2; j++)
                b[0][j] = *(const short8*)&Bs[cur][wn + j * 16 + t][ca];
        }
        __builtin_amdgcn_sched_barrier(0);   // pin group order for counted wait
        // s=1 read group (6 ds_read_b128)
        {
            const int ca = ((4 + g) ^ xorc) * 8;
#pragma unroll
            for (int i = 0; i < 4; i++)
                a[1][i] = *(const short8*)&As[cur][wm + i * 16 + t][ca];
#pragma unroll
            for (int j = 0; j < 2; j++)
                b[1][j] = *(const short8*)&Bs[cur][wn + j * 16 + t][ca];
        }
        asm volatile("s_waitcnt lgkmcnt(6)" ::: "memory");   // s=0 ready
        __builtin_amdgcn_sched_barrier(0);

        __builtin_amdgcn_s_setprio(1);       // s=0 MFMAs under s=1 read latency
#pragma unroll
        for (int i = 0; i < 4; i++)
#pragma unroll
            for (int j = 0; j < 2; j++)
                acc[i][j] = __builtin_amdgcn_mfma_f32_16x16x32_bf16(
                    a[0][i], b[0][j], acc[i][j], 0, 0, 0);
        __builtin_amdgcn_s_setprio(0);
        __builtin_amdgcn_sched_barrier(0);

        asm volatile("s_waitcnt lgkmcnt(0)" ::: "memory");   // all reads done
        __builtin_amdgcn_sched_barrier(0);
        __builtin_amdgcn_s_barrier();        // all waves done reading buf[cur]
        __builtin_amdgcn_sched_barrier(0);
        if (kt + 2 < nsteps) stage(cur, kt + 2);  // overwrite freed buffer

        __builtin_amdgcn_s_setprio(1);
#pragma unroll
        for (int i = 0; i < 4; i++)
#pragma unroll
            for (int j = 0; j < 2; j++)
                acc[i][j] = __builtin_amdgcn_mfma_f32_16x16x32_bf16(
                    a[1][i], b[1][j], acc[i][j], 0, 0, 0);
        __builtin_amdgcn_s_setprio(0);
        __builtin_amdgcn_sched_barrier(0);

        if (kt + 2 < nsteps) {
            asm volatile("s_waitcnt vmcnt(4)" ::: "memory");   // t+1 done, t+2 in flight
        } else if (kt + 1 < nsteps) {
            asm volatile("s_waitcnt vmcnt(0)" ::: "memory");   // last prefetched tile
        }
        __builtin_amdgcn_sched_barrier(0);
        if (kt + 1 < nsteps) __builtin_amdgcn_s_barrier();
        __builtin_amdgcn_sched_barrier(0);
    }

#pragma unroll
    for (int j = 0; j < 2; j++) {
        int col = n0 + wn + j * 16 + t;
        float bv = bias[col];
        if (QKV_MODE && col >= 1536) {
            int h = (col - 1536) >> 6, d = col & 63;
#pragma unroll
            for (int i = 0; i < 4; i++) {
                int n = m0 + wm + i * 16 + g * 4;
                int bb = n >> 10, nn = n & 1023;
                uint2v u;
                u.x = pack_bf16(acc[i][j][0] + bv, acc[i][j][1] + bv);
                u.y = pack_bf16(acc[i][j][2] + bv, acc[i][j][3] + bv);
                *(uint2v*)&Vt[(((size_t)bb * 12 + h) * 64 + d) * 1024 + nn] = u;
            }
        } else {
#pragma unroll
            for (int i = 0; i < 4; i++)
#pragma unroll
                for (int r = 0; r < 4; r++) {
                    int row = m0 + wm + i * 16 + g * 4 + r;
                    float val = acc[i][j][r] + bv;
                    if (QKV_MODE && col < 768) val *= QSCALE;
                    if (OUT_FP32) ((float*)C)[(size_t)row * ldc + col] = val;
                    else          ((ushort*)C)[(size_t)row * ldc + col] = f2bf(val);
                }
        }
    }
}

// ---------------- flash attention (S^T, fixed-max, q-tile 64) ----------------
// R14: counted-lgkmcnt split — issue 8 K reads, then 8 V reads, wait
// lgkmcnt(8) (K ready, V in flight), run QK^T UNDER the V read latency,
// then lgkmcnt(0) -> barrier (buf-reuse safety unchanged) -> stage ->
// softmax -> PV. Barrier count and vmcnt protocol identical to R12.
// LDS map (32 KB): K[buf] at byte buf*8192; V[buf] at 16384 + buf*8192.
__global__ __launch_bounds__(256) void attn_kernel(
    const ushort* __restrict__ qk, const ushort* __restrict__ Vt,
    ushort* __restrict__ out)
{
    __shared__ __attribute__((aligned(16))) ushort lds[16384];   // 32 KB

    const int tid  = threadIdx.x;
    const int lane = tid & 63;
    const int w    = tid >> 6;
    const int g    = lane >> 4;
    const int t    = lane & 15;
    const int bh   = blockIdx.x;
    const int b    = bh / 12;
    const int h    = bh - b * 12;
    const int q0   = blockIdx.y * 64;

    const size_t base  = (size_t)b * 1024 * 1536;
    const size_t vbase = ((size_t)b * 12 + h) * 64 * 1024;

    short8 qfrag[2];
#pragma unroll
    for (int s = 0; s < 2; s++)
        qfrag[s] = *(const short8*)&qk[base +
            (size_t)(q0 + w * 16 + t) * 1536 + h * 64 + s * 32 + g * 8];

    // hoisted per-lane LDS read byte offsets (identical for K and V)
    int offr[2][4];
#pragma unroll
    for (int s = 0; s < 2; s++)
#pragma unroll
        for (int j = 0; j < 4; j++)
            offr[s][j] = (j * 16 + t) * 128 + (((s * 4 + g) ^ (t & 7)) * 16);

    // staging: wave w stages rows w*16 + p*8 .. +7 (p=0,1); lane l covers
    // row += (l>>3), phys chunk (l&7); source chunk = (l&7)^(row&7).
    const int lr = lane >> 3, pc = lane & 7;
    const ushort* kg[2];
    const ushort* vg[2];
#pragma unroll
    for (int p = 0; p < 2; p++) {
        const int row = w * 16 + p * 8 + lr;
        const int gc  = pc ^ (row & 7);
        kg[p] = qk + base + (size_t)row * 1536 + 768 + h * 64 + gc * 8;
        vg[p] = Vt + vbase + (size_t)row * 1024 + gc * 8;
    }

    auto stage = [&](int buf) {   // 4 gload_lds per wave; advances pointers
#pragma unroll
        for (int p = 0; p < 2; p++) {
            ushort* kd = lds + buf * 4096 + (w * 16 + p * 8) * 64;
            ushort* vd = lds + 8192 + buf * 4096 + (w * 16 + p * 8) * 64;
            gload_lds16(kg[p], kd); kg[p] += 64 * 1536;
            gload_lds16(vg[p], vd); vg[p] += 64;
        }
    };

    // prologue: 2-deep prefetch; wait own tile-0 loads, barrier for all waves
    stage(0);
    stage(1);
    asm volatile("s_waitcnt vmcnt(4)" ::: "memory");
    __builtin_amdgcn_sched_barrier(0);
    __builtin_amdgcn_s_barrier();
    __builtin_amdgcn_sched_barrier(0);

    f32x4 o_acc[4];
#pragma unroll
    for (int j = 0; j < 4; j++) o_acc[j] = {0.f, 0.f, 0.f, 0.f};
    float l_part = 0.f;

    auto tile = [&](int kt, int cur) {
        short8 kf[2][4], bv[2][4];
        // K read group (8 ds_read_b128)
#pragma unroll
        for (int s = 0; s < 2; s++)
#pragma unroll
            for (int j = 0; j < 4; j++)
                kf[s][j] = *(const short8*)((const char*)lds + cur * 8192 + offr[s][j]);
        __builtin_amdgcn_sched_barrier(0);   // pin group order for counted wait
        // V read group (8 ds_read_b128)
#pragma unroll
        for (int s = 0; s < 2; s++)
#pragma unroll
            for (int j = 0; j < 4; j++)
                bv[s][j] = *(const short8*)((const char*)lds + 16384 + cur * 8192 + offr[s][j]);
        asm volatile("s_waitcnt lgkmcnt(8)" ::: "memory");   // K ready, V in flight
        __builtin_amdgcn_sched_barrier(0);

        // QK^T under the V reads' latency
        f32x4 s_acc[4];
#pragma unroll
        for (int j = 0; j < 4; j++) s_acc[j] = {0.f, 0.f, 0.f, 0.f};
        __builtin_amdgcn_s_setprio(1);
#pragma unroll
        for (int s = 0; s < 2; s++)
#pragma unroll
            for (int j = 0; j < 4; j++)
                s_acc[j] = __builtin_amdgcn_mfma_f32_16x16x32_bf16(
                    kf[s][j], qfrag[s], s_acc[j], 0, 0, 0);
        __builtin_amdgcn_s_setprio(0);
        __builtin_amdgcn_sched_barrier(0);

        asm volatile("s_waitcnt lgkmcnt(0)" ::: "memory");   // all reads done
        __builtin_amdgcn_sched_barrier(0);
        __builtin_amdgcn_s_barrier();          // all waves done reading buf[cur]
        __builtin_amdgcn_sched_barrier(0);
        if (kt + 2 < 16) stage(cur);           // refill freed buffer (tile kt+2)

        // softmax numerator + pack to bf16 words w[j][h]
        u32 wj[4][2];
#pragma unroll
        for (int j = 0; j < 4; j++) {
            float p0 = __builtin_amdgcn_exp2f(s_acc[j][0]);
            float p1 = __builtin_amdgcn_exp2f(s_acc[j][1]);
            float p2 = __builtin_amdgcn_exp2f(s_acc[j][2]);
            float p3 = __builtin_amdgcn_exp2f(s_acc[j][3]);
            l_part += (p0 + p1) + (p2 + p3);
            wj[j][0] = pack_bf16(p0, p1);
            wj[j][1] = pack_bf16(p2, p3);
        }

        // in-register P^T -> A-fragment reshuffle (permlane, no LDS)
        __builtin_amdgcn_s_setprio(1);
#pragma unroll
        for (int s = 0; s < 2; s++) {
            auto r0 = __builtin_amdgcn_permlane32_swap(wj[2 * s][0], wj[2 * s + 1][0], false, false);
            auto r1 = __builtin_amdgcn_permlane32_swap(wj[2 * s][1], wj[2 * s + 1][1], false, false);
            auto m02 = __builtin_amdgcn_permlane16_swap(r0[0], r0[1], false, false);
            auto m13 = __builtin_amdgcn_permlane16_swap(r1[0], r1[1], false, false);
            uint4v av;
            av.x = m02[0];
            av.y = m13[0];
            av.z = m02[1];
            av.w = m13[1];
            short8 a = __builtin_bit_cast(short8, av);
#pragma unroll
            for (int j = 0; j < 4; j++)
                o_acc[j] = __builtin_amdgcn_mfma_f32_16x16x32_bf16(
                    a, bv[s][j], o_acc[j], 0, 0, 0);
        }
        __builtin_amdgcn_s_setprio(0);
        __builtin_amdgcn_sched_barrier(0);

        if (kt + 2 < 16) {
            asm volatile("s_waitcnt vmcnt(4)" ::: "memory");  // kt+1 landed, kt+2 in flight
        } else if (kt == 14) {
            asm volatile("s_waitcnt vmcnt(0)" ::: "memory");  // last tile's staging
        }
        __builtin_amdgcn_sched_barrier(0);
        if (kt < 15) __builtin_amdgcn_s_barrier();
        __builtin_amdgcn_sched_barrier(0);
    };

    for (int m = 0; m < 8; m++) {
        tile(2 * m, 0);       // cur as literal -> LDS offsets fold to immediates
        tile(2 * m + 1, 1);
    }

    // epilogue
    {
        float l_tot = l_part;
        l_tot += __shfl_xor(l_tot, 16);
        l_tot += __shfl_xor(l_tot, 32);
        float il[4];
#pragma unroll
        for (int r = 0; r < 4; r++) il[r] = 1.0f / __shfl(l_tot, g * 4 + r);
#pragma unroll
        for (int r = 0; r < 4; r++) {
            int row = q0 + w * 16 + g * 4 + r;
#pragma unroll
            for (int j = 0; j < 4; j++)
                out[((size_t)(b * 1024 + row)) * 768 + h * 64 + j * 16 + t] =
                    f2bf(o_acc[j][r] * il[r]);
        }
    }
}

extern "C" void kernel_launch(void* const* d_in, const int* in_sizes, int n_in,
                              void* d_out, int out_size, void* d_ws, size_t ws_size,
                              hipStream_t stream)
{
    const float* x      = (const float*)d_in[0];  // [8,1024,768] fp32
    const float* qkv_w  = (const float*)d_in[1];  // [768,2304]   fp32
    const float* qkv_b  = (const float*)d_in[2];  // [2304]       fp32
    const float* proj_w = (const float*)d_in[3];  // [768,768]    fp32
    const float* proj_b = (const float*)d_in[4];  // [768]        fp32
    float* out = (float*)d_out;                   // [8,1024,768] fp32

    char* ws = (char*)d_ws;
    ushort* Wt1 = (ushort*)ws;                               // 2304*768 bf16
    ushort* Wt2 = Wt1 + (size_t)2304 * 768;                  // 768*768  bf16
    char*   buf = (char*)(Wt2 + (size_t)768 * 768);

    const size_t wt_bytes   = ((size_t)2304 * 768 + (size_t)768 * 768) * 2;
    const size_t full_bytes = wt_bytes + (size_t)8192 * 768 * 2    // xb
                                       + (size_t)8192 * 1536 * 2   // qk
                                       + (size_t)8192 * 768 * 2    // Vt
                                       + (size_t)8192 * 768 * 2;   // attnO

    if (ws_size >= full_bytes) {
        ushort* xb    = (ushort*)buf;
        ushort* qkO   = xb + (size_t)8192 * 768;
        ushort* VtO   = qkO + (size_t)8192 * 1536;
        ushort* attnO = VtO + (size_t)8192 * 768;
        prep_kernel<<<dim3(5376), 256, 0, stream>>>(x, xb, qkv_w, Wt1, proj_w, Wt2);
        gemm_bt<false, true><<<dim3(64, 18), 512, 0, stream>>>(
            xb, Wt1, qkv_b, qkO, VtO, 8192, 2304, 768, 1536);
        attn_kernel<<<dim3(96, 16), 256, 0, stream>>>(qkO, VtO, attnO);
        gemm_bt<true, false><<<dim3(64, 6), 512, 0, stream>>>(
            attnO, Wt2, proj_b, out, nullptr, 8192, 768, 768, 768);
    } else {
        // Per-batch path: ~13 MB workspace.
        transpose_f32_bf16<<<dim3(72, 24), 256, 0, stream>>>(qkv_w, Wt1, 768, 2304);
        transpose_f32_bf16<<<dim3(24, 24), 256, 0, stream>>>(proj_w, Wt2, 768, 768);
        ushort* xbB   = (ushort*)buf;
        ushort* qkB   = xbB + (size_t)1024 * 768;
        ushort* VtB   = qkB + (size_t)1024 * 1536;
        ushort* attnB = VtB + (size_t)1024 * 768;
        for (int b = 0; b < 8; b++) {
            const float* xp = x + (size_t)b * 1024 * 768;
            float* outb = out + (size_t)b * 1024 * 768;
            convert_f32_bf16<<<dim3(384), 256, 0, stream>>>(xp, xbB, 98304);
            gemm_bt<false, true><<<dim3(8, 18), 512, 0, stream>>>(
                xbB, Wt1, qkv_b, qkB, VtB, 1024, 2304, 768, 1536);
            attn_kernel<<<dim3(12, 16), 256, 0, stream>>>(qkB, VtB, attnB);
            gemm_bt<true, false><<<dim3(8, 6), 512, 0, stream>>>(
                attnB, Wt2, proj_b, outb, nullptr, 1024, 768, 768, 768);
        }
    }
}

// Round 15
// 181.975 us; speedup vs baseline: 1.0172x; 1.0172x over previous
//
#include <hip/hip_runtime.h>
#include <hip/hip_bf16.h>

typedef __attribute__((ext_vector_type(8))) short short8;
typedef __attribute__((ext_vector_type(4))) float f32x4;
typedef __attribute__((ext_vector_type(2))) unsigned int uint2v;
typedef __attribute__((ext_vector_type(4))) unsigned int uint4v;
typedef unsigned int u32;

#define QSCALE 0.1803368801111204f  // 0.125 * log2(e), folded into Q

__device__ inline ushort f2bf(float f) {
    unsigned int i = __builtin_bit_cast(unsigned int, f);
    unsigned int r = (i + 0x7FFFu + ((i >> 16) & 1u)) >> 16;  // RNE
    return (ushort)r;
}
// hardware v_cvt_pk_bf16_f32 (memcpy dodges non-trivially-copyable bit_cast)
__device__ inline u32 pack_bf16(float a, float b) {
    float2 f2; f2.x = a; f2.y = b;
    __hip_bfloat162 h = __float22bfloat162_rn(f2);
    u32 r; __builtin_memcpy(&r, &h, 4);
    return r;
}

// async 16B global->LDS (lane i lands at wave-uniform base + i*16)
__device__ __forceinline__ void gload_lds16(const ushort* g, ushort* l) {
    __builtin_amdgcn_global_load_lds(
        (const __attribute__((address_space(1))) u32*)g,
        (__attribute__((address_space(3))) u32*)l, 16, 0, 0);
}

// -------- convert: x fp32 -> bf16, 8 elems/thread (per-batch fallback) -------
__global__ __launch_bounds__(256) void convert_f32_bf16(
    const float* __restrict__ in, ushort* __restrict__ outp, int n8)
{
    int idx = blockIdx.x * 256 + threadIdx.x;
    if (idx >= n8) return;
    const float4 u0 = *(const float4*)&in[(size_t)idx * 8];
    const float4 u1 = *(const float4*)&in[(size_t)idx * 8 + 4];
    uint2v a, b;
    a.x = pack_bf16(u0.x, u0.y); a.y = pack_bf16(u0.z, u0.w);
    b.x = pack_bf16(u1.x, u1.y); b.y = pack_bf16(u1.z, u1.w);
    *(uint2v*)&outp[(size_t)idx * 8] = a;
    *(uint2v*)&outp[(size_t)idx * 8 + 4] = b;
}

// -------- transpose+convert: W[K][N] (fp32) -> Wt[N][K] (bf16) (fallback) ----
__global__ __launch_bounds__(256) void transpose_f32_bf16(
    const float* __restrict__ W, ushort* __restrict__ Wt, int K, int N)
{
    __shared__ float tile[32][33];
    const int n0 = blockIdx.x * 32;
    const int k0 = blockIdx.y * 32;
    const int tx = threadIdx.x & 31;
    const int ty = threadIdx.x >> 5;
    for (int i = ty; i < 32; i += 8)
        tile[i][tx] = W[(size_t)(k0 + i) * N + n0 + tx];
    __syncthreads();
    for (int i = ty; i < 32; i += 8)
        Wt[(size_t)(n0 + i) * K + k0 + tx] = f2bf(tile[tx][i]);
}

// -------- fused prep: convert(x) + transpose(qkv_w) + transpose(proj_w) ------
// blocks [0,3072): convert; [3072,4800): W1 72x24; [4800,5376): W2 24x24.
__global__ __launch_bounds__(256) void prep_kernel(
    const float* __restrict__ x, ushort* __restrict__ xb,
    const float* __restrict__ qkv_w, ushort* __restrict__ Wt1,
    const float* __restrict__ proj_w, ushort* __restrict__ Wt2)
{
    __shared__ float tile[32][33];
    const int blk = blockIdx.x;
    if (blk < 3072) {
        const int idx = blk * 256 + threadIdx.x;
        const float4 u0 = *(const float4*)&x[(size_t)idx * 8];
        const float4 u1 = *(const float4*)&x[(size_t)idx * 8 + 4];
        uint2v a, b;
        a.x = pack_bf16(u0.x, u0.y); a.y = pack_bf16(u0.z, u0.w);
        b.x = pack_bf16(u1.x, u1.y); b.y = pack_bf16(u1.z, u1.w);
        *(uint2v*)&xb[(size_t)idx * 8] = a;
        *(uint2v*)&xb[(size_t)idx * 8 + 4] = b;
        return;
    }
    const float* W;  ushort* Wt;  int K, N, n0, k0;
    if (blk < 4800) {
        const int i = blk - 3072;
        W = qkv_w; Wt = Wt1; K = 768; N = 2304;
        n0 = (i % 72) * 32; k0 = (i / 72) * 32;
    } else {
        const int i = blk - 4800;
        W = proj_w; Wt = Wt2; K = 768; N = 768;
        n0 = (i % 24) * 32; k0 = (i / 24) * 32;
    }
    const int tx = threadIdx.x & 31;
    const int ty = threadIdx.x >> 5;
    for (int i = ty; i < 32; i += 8)
        tile[i][tx] = W[(size_t)(k0 + i) * N + n0 + tx];
    __syncthreads();
    for (int i = ty; i < 32; i += 8)
        Wt[(size_t)(n0 + i) * K + k0 + tx] = f2bf(tile[tx][i]);
}

// ------ GEMM (128x128 tile, 8 WAVES, BK=64, dbuf, counted-vmcnt) ------
// R14 structure kept (counted lgkmcnt split neutral but harmless).
// QKV_MODE: col<768 (Q) -> *QSCALE ->C; col<1536 (K) -> C; else (V) -> Vt
template <bool OUT_FP32, bool QKV_MODE>
__global__ __launch_bounds__(512) void gemm_bt(
    const ushort* __restrict__ A, const ushort* __restrict__ Bt,
    const float* __restrict__ bias, void* __restrict__ C,
    ushort* __restrict__ Vt, int M, int N, int K, int ldc)
{
    __shared__ __attribute__((aligned(16))) ushort As[2][128][64];
    __shared__ __attribute__((aligned(16))) ushort Bs[2][128][64];
    const int tid  = threadIdx.x;
    const int lane = tid & 63;
    const int w    = tid >> 6;            // 0..7
    const int wm   = (w >> 2) * 64;       // wave-row: 2 groups of 64 rows
    const int wn   = (w & 3) * 32;        // wave-col: 4 groups of 32 cols
    const int g    = lane >> 4;
    const int t    = lane & 15;
    const int m0   = blockIdx.x * 128;
    const int n0   = blockIdx.y * 128;

    const int lr = lane >> 3;       // 0..7
    const int pc = lane & 7;        // 0..7
    const int xorc = t & 7;

    f32x4 acc[4][2];
#pragma unroll
    for (int i = 0; i < 4; i++)
#pragma unroll
        for (int j = 0; j < 2; j++) acc[i][j] = {0.f, 0.f, 0.f, 0.f};

    const int nsteps = K >> 6;

    auto stage = [&](int buf, int kt) {   // 4 gload_lds per wave (A:2, B:2)
        const int k0 = kt * 64;
#pragma unroll
        for (int p = 0; p < 2; p++) {
            const int row = p * 64 + w * 8 + lr;            // 0..127
            const int gc  = pc ^ (row & 7);
            gload_lds16(&A[(size_t)(m0 + row) * K + k0 + gc * 8], &As[buf][p * 64 + w * 8][0]);
            gload_lds16(&Bt[(size_t)(n0 + row) * K + k0 + gc * 8], &Bs[buf][p * 64 + w * 8][0]);
        }
    };

    // prologue: 2-deep prefetch; wait only tile 0 (4 of 8 outstanding)
    stage(0, 0);
    stage(1, 1);
    asm volatile("s_waitcnt vmcnt(4)" ::: "memory");
    __builtin_amdgcn_sched_barrier(0);
    __builtin_amdgcn_s_barrier();
    __builtin_amdgcn_sched_barrier(0);

    for (int kt = 0; kt < nsteps; kt++) {
        const int cur = kt & 1;
        short8 a[2][4], b[2][2];
        // s=0 read group (6 ds_read_b128)
        {
            const int ca = (g ^ xorc) * 8;
#pragma unroll
            for (int i = 0; i < 4; i++)
                a[0][i] = *(const short8*)&As[cur][wm + i * 16 + t][ca];
#pragma unroll
            for (int j = 0; j < 2; j++)
                b[0][j] = *(const short8*)&Bs[cur][wn + j * 16 + t][ca];
        }
        __builtin_amdgcn_sched_barrier(0);   // pin group order for counted wait
        // s=1 read group (6 ds_read_b128)
        {
            const int ca = ((4 + g) ^ xorc) * 8;
#pragma unroll
            for (int i = 0; i < 4; i++)
                a[1][i] = *(const short8*)&As[cur][wm + i * 16 + t][ca];
#pragma unroll
            for (int j = 0; j < 2; j++)
                b[1][j] = *(const short8*)&Bs[cur][wn + j * 16 + t][ca];
        }
        asm volatile("s_waitcnt lgkmcnt(6)" ::: "memory");   // s=0 ready
        __builtin_amdgcn_sched_barrier(0);

        __builtin_amdgcn_s_setprio(1);       // s=0 MFMAs under s=1 read latency
#pragma unroll
        for (int i = 0; i < 4; i++)
#pragma unroll
            for (int j = 0; j < 2; j++)
                acc[i][j] = __builtin_amdgcn_mfma_f32_16x16x32_bf16(
                    a[0][i], b[0][j], acc[i][j], 0, 0, 0);
        __builtin_amdgcn_s_setprio(0);
        __builtin_amdgcn_sched_barrier(0);

        asm volatile("s_waitcnt lgkmcnt(0)" ::: "memory");   // all reads done
        __builtin_amdgcn_sched_barrier(0);
        __builtin_amdgcn_s_barrier();        // all waves done reading buf[cur]
        __builtin_amdgcn_sched_barrier(0);
        if (kt + 2 < nsteps) stage(cur, kt + 2);  // overwrite freed buffer

        __builtin_amdgcn_s_setprio(1);
#pragma unroll
        for (int i = 0; i < 4; i++)
#pragma unroll
            for (int j = 0; j < 2; j++)
                acc[i][j] = __builtin_amdgcn_mfma_f32_16x16x32_bf16(
                    a[1][i], b[1][j], acc[i][j], 0, 0, 0);
        __builtin_amdgcn_s_setprio(0);
        __builtin_amdgcn_sched_barrier(0);

        if (kt + 2 < nsteps) {
            asm volatile("s_waitcnt vmcnt(4)" ::: "memory");   // t+1 done, t+2 in flight
        } else if (kt + 1 < nsteps) {
            asm volatile("s_waitcnt vmcnt(0)" ::: "memory");   // last prefetched tile
        }
        __builtin_amdgcn_sched_barrier(0);
        if (kt + 1 < nsteps) __builtin_amdgcn_s_barrier();
        __builtin_amdgcn_sched_barrier(0);
    }

#pragma unroll
    for (int j = 0; j < 2; j++) {
        int col = n0 + wn + j * 16 + t;
        float bv = bias[col];
        if (QKV_MODE && col >= 1536) {
            int h = (col - 1536) >> 6, d = col & 63;
#pragma unroll
            for (int i = 0; i < 4; i++) {
                int n = m0 + wm + i * 16 + g * 4;
                int bb = n >> 10, nn = n & 1023;
                uint2v u;
                u.x = pack_bf16(acc[i][j][0] + bv, acc[i][j][1] + bv);
                u.y = pack_bf16(acc[i][j][2] + bv, acc[i][j][3] + bv);
                *(uint2v*)&Vt[(((size_t)bb * 12 + h) * 64 + d) * 1024 + nn] = u;
            }
        } else {
#pragma unroll
            for (int i = 0; i < 4; i++)
#pragma unroll
                for (int r = 0; r < 4; r++) {
                    int row = m0 + wm + i * 16 + g * 4 + r;
                    float val = acc[i][j][r] + bv;
                    if (QKV_MODE && col < 768) val *= QSCALE;
                    if (OUT_FP32) ((float*)C)[(size_t)row * ldc + col] = val;
                    else          ((ushort*)C)[(size_t)row * ldc + col] = f2bf(val);
                }
        }
    }
}

// ------ GEMM small-N (64x128 tile, BK=64, dbuf, counted-vmcnt): proj ------
// R15: restored (R12's best-measured proj config — 768 blocks x 256 thr =
// 3 blocks/CU balanced; the 384x512 gemm_bt variant left half the CUs with
// a 2-block tail: R12=183.0 vs R13/14=184.9/185.1).
__global__ __launch_bounds__(256) void gemm_bt2(
    const ushort* __restrict__ A, const ushort* __restrict__ Bt,
    const float* __restrict__ bias, float* __restrict__ C,
    int M, int N, int K, int ldc)
{
    __shared__ __attribute__((aligned(16))) ushort As[2][64][64];
    __shared__ __attribute__((aligned(16))) ushort Bs[2][128][64];
    const int tid  = threadIdx.x;
    const int lane = tid & 63;
    const int w    = tid >> 6;
    const int g    = lane >> 4;
    const int t    = lane & 15;
    const int m0   = blockIdx.x * 64;
    const int n0   = blockIdx.y * 128;
    const int wn   = w * 32;

    const int lr = lane >> 3;
    const int pc = lane & 7;
    const int xorc = t & 7;

    f32x4 acc[4][2];
#pragma unroll
    for (int i = 0; i < 4; i++)
#pragma unroll
        for (int j = 0; j < 2; j++) acc[i][j] = {0.f, 0.f, 0.f, 0.f};

    const int nsteps = K >> 6;

    auto stage = [&](int buf, int kt) {   // 6 gload_lds per wave
        const int k0 = kt * 64;
#pragma unroll
        for (int p = 0; p < 2; p++) {
            const int row = w * 16 + p * 8 + lr;
            const int gc  = pc ^ (row & 7);
            gload_lds16(&A[(size_t)(m0 + row) * K + k0 + gc * 8], &As[buf][w * 16 + p * 8][0]);
        }
#pragma unroll
        for (int p = 0; p < 4; p++) {
            const int row = w * 32 + p * 8 + lr;
            const int gc  = pc ^ (row & 7);
            gload_lds16(&Bt[(size_t)(n0 + row) * K + k0 + gc * 8], &Bs[buf][w * 32 + p * 8][0]);
        }
    };

    stage(0, 0);
    stage(1, 1);
    asm volatile("s_waitcnt vmcnt(6)" ::: "memory");
    __builtin_amdgcn_sched_barrier(0);
    __builtin_amdgcn_s_barrier();
    __builtin_amdgcn_sched_barrier(0);

    for (int kt = 0; kt < nsteps; kt++) {
        const int cur = kt & 1;
        short8 a[2][4], b[2][2];
#pragma unroll
        for (int s = 0; s < 2; s++) {
            const int ca = ((s * 4 + g) ^ xorc) * 8;
#pragma unroll
            for (int i = 0; i < 4; i++)
                a[s][i] = *(const short8*)&As[cur][i * 16 + t][ca];
#pragma unroll
            for (int j = 0; j < 2; j++)
                b[s][j] = *(const short8*)&Bs[cur][wn + j * 16 + t][ca];
        }
        asm volatile("s_waitcnt lgkmcnt(0)" ::: "memory");
        __builtin_amdgcn_sched_barrier(0);
        __builtin_amdgcn_s_barrier();
        __builtin_amdgcn_sched_barrier(0);
        if (kt + 2 < nsteps) stage(cur, kt + 2);

        __builtin_amdgcn_s_setprio(1);
#pragma unroll
        for (int s = 0; s < 2; s++)
#pragma unroll
            for (int i = 0; i < 4; i++)
#pragma unroll
                for (int j = 0; j < 2; j++)
                    acc[i][j] = __builtin_amdgcn_mfma_f32_16x16x32_bf16(
                        a[s][i], b[s][j], acc[i][j], 0, 0, 0);
        __builtin_amdgcn_s_setprio(0);
        __builtin_amdgcn_sched_barrier(0);

        if (kt + 2 < nsteps) {
            asm volatile("s_waitcnt vmcnt(6)" ::: "memory");
        } else if (kt + 1 < nsteps) {
            asm volatile("s_waitcnt vmcnt(0)" ::: "memory");
        }
        __builtin_amdgcn_sched_barrier(0);
        if (kt + 1 < nsteps) __builtin_amdgcn_s_barrier();
        __builtin_amdgcn_sched_barrier(0);
    }

#pragma unroll
    for (int j = 0; j < 2; j++) {
        int col = n0 + wn + j * 16 + t;
        float bv = bias[col];
#pragma unroll
        for (int i = 0; i < 4; i++)
#pragma unroll
            for (int r = 0; r < 4; r++) {
                int row = m0 + i * 16 + g * 4 + r;
                C[(size_t)row * ldc + col] = acc[i][j][r] + bv;
            }
    }
}

// ---------------- flash attention (S^T, fixed-max, q-tile 64) ----------------
// R15: softmax denominator folded into the MFMA pipe — lacc = mfma(P, ones)
// replaces per-tile 16 v_add (VALU 54% busy) with 2 MFMA (pipe 21% busy),
// AND kills the epilogue shfl reduction: lacc[r] lands q-indexed per lane
// (D row = g*4+r = q-row, col value independent of t).
// Pipeline unchanged: gload_lds pre-swizzled source, counted vmcnt(4)/
// lgkmcnt(8), raw s_barrier + sched_barrier fences, hoisted offsets.
// LDS map (32 KB): K[buf] at byte buf*8192; V[buf] at 16384 + buf*8192.
__global__ __launch_bounds__(256) void attn_kernel(
    const ushort* __restrict__ qk, const ushort* __restrict__ Vt,
    ushort* __restrict__ out)
{
    __shared__ __attribute__((aligned(16))) ushort lds[16384];   // 32 KB

    const int tid  = threadIdx.x;
    const int lane = tid & 63;
    const int w    = tid >> 6;
    const int g    = lane >> 4;
    const int t    = lane & 15;
    const int bh   = blockIdx.x;
    const int b    = bh / 12;
    const int h    = bh - b * 12;
    const int q0   = blockIdx.y * 64;

    const size_t base  = (size_t)b * 1024 * 1536;
    const size_t vbase = ((size_t)b * 12 + h) * 64 * 1024;

    short8 qfrag[2];
#pragma unroll
    for (int s = 0; s < 2; s++)
        qfrag[s] = *(const short8*)&qk[base +
            (size_t)(q0 + w * 16 + t) * 1536 + h * 64 + s * 32 + g * 8];

    // all-ones bf16 fragment for the l-sum MFMA
    short8 ones;
#pragma unroll
    for (int i = 0; i < 8; i++) ones[i] = (short)0x3F80;

    // hoisted per-lane LDS read byte offsets (identical for K and V)
    int offr[2][4];
#pragma unroll
    for (int s = 0; s < 2; s++)
#pragma unroll
        for (int j = 0; j < 4; j++)
            offr[s][j] = (j * 16 + t) * 128 + (((s * 4 + g) ^ (t & 7)) * 16);

    // staging: wave w stages rows w*16 + p*8 .. +7 (p=0,1); lane l covers
    // row += (l>>3), phys chunk (l&7); source chunk = (l&7)^(row&7).
    const int lr = lane >> 3, pc = lane & 7;
    const ushort* kg[2];
    const ushort* vg[2];
#pragma unroll
    for (int p = 0; p < 2; p++) {
        const int row = w * 16 + p * 8 + lr;
        const int gc  = pc ^ (row & 7);
        kg[p] = qk + base + (size_t)row * 1536 + 768 + h * 64 + gc * 8;
        vg[p] = Vt + vbase + (size_t)row * 1024 + gc * 8;
    }

    auto stage = [&](int buf) {   // 4 gload_lds per wave; advances pointers
#pragma unroll
        for (int p = 0; p < 2; p++) {
            ushort* kd = lds + buf * 4096 + (w * 16 + p * 8) * 64;
            ushort* vd = lds + 8192 + buf * 4096 + (w * 16 + p * 8) * 64;
            gload_lds16(kg[p], kd); kg[p] += 64 * 1536;
            gload_lds16(vg[p], vd); vg[p] += 64;
        }
    };

    // prologue: 2-deep prefetch; wait own tile-0 loads, barrier for all waves
    stage(0);
    stage(1);
    asm volatile("s_waitcnt vmcnt(4)" ::: "memory");
    __builtin_amdgcn_sched_barrier(0);
    __builtin_amdgcn_s_barrier();
    __builtin_amdgcn_sched_barrier(0);

    f32x4 o_acc[4];
#pragma unroll
    for (int j = 0; j < 4; j++) o_acc[j] = {0.f, 0.f, 0.f, 0.f};
    f32x4 lacc = {0.f, 0.f, 0.f, 0.f};

    auto tile = [&](int kt, int cur) {
        short8 kf[2][4], bv[2][4];
        // K read group (8 ds_read_b128)
#pragma unroll
        for (int s = 0; s < 2; s++)
#pragma unroll
            for (int j = 0; j < 4; j++)
                kf[s][j] = *(const short8*)((const char*)lds + cur * 8192 + offr[s][j]);
        __builtin_amdgcn_sched_barrier(0);   // pin group order for counted wait
        // V read group (8 ds_read_b128)
#pragma unroll
        for (int s = 0; s < 2; s++)
#pragma unroll
            for (int j = 0; j < 4; j++)
                bv[s][j] = *(const short8*)((const char*)lds + 16384 + cur * 8192 + offr[s][j]);
        asm volatile("s_waitcnt lgkmcnt(8)" ::: "memory");   // K ready, V in flight
        __builtin_amdgcn_sched_barrier(0);

        // QK^T under the V reads' latency
        f32x4 s_acc[4];
#pragma unroll
        for (int j = 0; j < 4; j++) s_acc[j] = {0.f, 0.f, 0.f, 0.f};
        __builtin_amdgcn_s_setprio(1);
#pragma unroll
        for (int s = 0; s < 2; s++)
#pragma unroll
            for (int j = 0; j < 4; j++)
                s_acc[j] = __builtin_amdgcn_mfma_f32_16x16x32_bf16(
                    kf[s][j], qfrag[s], s_acc[j], 0, 0, 0);
        __builtin_amdgcn_s_setprio(0);
        __builtin_amdgcn_sched_barrier(0);

        asm volatile("s_waitcnt lgkmcnt(0)" ::: "memory");   // all reads done
        __builtin_amdgcn_sched_barrier(0);
        __builtin_amdgcn_s_barrier();          // all waves done reading buf[cur]
        __builtin_amdgcn_sched_barrier(0);
        if (kt + 2 < 16) stage(cur);           // refill freed buffer (tile kt+2)

        // softmax numerator + pack to bf16 words w[j][h] (no l adds — MFMA'd)
        u32 wj[4][2];
#pragma unroll
        for (int j = 0; j < 4; j++) {
            float p0 = __builtin_amdgcn_exp2f(s_acc[j][0]);
            float p1 = __builtin_amdgcn_exp2f(s_acc[j][1]);
            float p2 = __builtin_amdgcn_exp2f(s_acc[j][2]);
            float p3 = __builtin_amdgcn_exp2f(s_acc[j][3]);
            wj[j][0] = pack_bf16(p0, p1);
            wj[j][1] = pack_bf16(p2, p3);
        }

        // in-register P^T -> A-fragment reshuffle (permlane, no LDS)
        __builtin_amdgcn_s_setprio(1);
#pragma unroll
        for (int s = 0; s < 2; s++) {
            auto r0 = __builtin_amdgcn_permlane32_swap(wj[2 * s][0], wj[2 * s + 1][0], false, false);
            auto r1 = __builtin_amdgcn_permlane32_swap(wj[2 * s][1], wj[2 * s + 1][1], false, false);
            auto m02 = __builtin_amdgcn_permlane16_swap(r0[0], r0[1], false, false);
            auto m13 = __builtin_amdgcn_permlane16_swap(r1[0], r1[1], false, false);
            uint4v av;
            av.x = m02[0];
            av.y = m13[0];
            av.z = m02[1];
            av.w = m13[1];
            short8 a = __builtin_bit_cast(short8, av);
#pragma unroll
            for (int j = 0; j < 4; j++)
                o_acc[j] = __builtin_amdgcn_mfma_f32_16x16x32_bf16(
                    a, bv[s][j], o_acc[j], 0, 0, 0);
            // l-sum on the MFMA pipe: row sums of P (B = ones), q-indexed
            lacc = __builtin_amdgcn_mfma_f32_16x16x32_bf16(a, ones, lacc, 0, 0, 0);
        }
        __builtin_amdgcn_s_setprio(0);
        __builtin_amdgcn_sched_barrier(0);

        if (kt + 2 < 16) {
            asm volatile("s_waitcnt vmcnt(4)" ::: "memory");  // kt+1 landed, kt+2 in flight
        } else if (kt == 14) {
            asm volatile("s_waitcnt vmcnt(0)" ::: "memory");  // last tile's staging
        }
        __builtin_amdgcn_sched_barrier(0);
        if (kt < 15) __builtin_amdgcn_s_barrier();
        __builtin_amdgcn_sched_barrier(0);
    };

    for (int m = 0; m < 8; m++) {
        tile(2 * m, 0);       // cur as literal -> LDS offsets fold to immediates
        tile(2 * m + 1, 1);
    }

    // epilogue: lacc[r] is already the full l for q-row g*4+r (every lane)
    {
        float il[4];
#pragma unroll
        for (int r = 0; r < 4; r++) il[r] = 1.0f / lacc[r];
#pragma unroll
        for (int r = 0; r < 4; r++) {
            int row = q0 + w * 16 + g * 4 + r;
#pragma unroll
            for (int j = 0; j < 4; j++)
                out[((size_t)(b * 1024 + row)) * 768 + h * 64 + j * 16 + t] =
                    f2bf(o_acc[j][r] * il[r]);
        }
    }
}

extern "C" void kernel_launch(void* const* d_in, const int* in_sizes, int n_in,
                              void* d_out, int out_size, void* d_ws, size_t ws_size,
                              hipStream_t stream)
{
    const float* x      = (const float*)d_in[0];  // [8,1024,768] fp32
    const float* qkv_w  = (const float*)d_in[1];  // [768,2304]   fp32
    const float* qkv_b  = (const float*)d_in[2];  // [2304]       fp32
    const float* proj_w = (const float*)d_in[3];  // [768,768]    fp32
    const float* proj_b = (const float*)d_in[4];  // [768]        fp32
    float* out = (float*)d_out;                   // [8,1024,768] fp32

    char* ws = (char*)d_ws;
    ushort* Wt1 = (ushort*)ws;                               // 2304*768 bf16
    ushort* Wt2 = Wt1 + (size_t)2304 * 768;                  // 768*768  bf16
    char*   buf = (char*)(Wt2 + (size_t)768 * 768);

    const size_t wt_bytes   = ((size_t)2304 * 768 + (size_t)768 * 768) * 2;
    const size_t full_bytes = wt_bytes + (size_t)8192 * 768 * 2    // xb
                                       + (size_t)8192 * 1536 * 2   // qk
                                       + (size_t)8192 * 768 * 2    // Vt
                                       + (size_t)8192 * 768 * 2;   // attnO

    if (ws_size >= full_bytes) {
        ushort* xb    = (ushort*)buf;
        ushort* qkO   = xb + (size_t)8192 * 768;
        ushort* VtO   = qkO + (size_t)8192 * 1536;
        ushort* attnO = VtO + (size_t)8192 * 768;
        prep_kernel<<<dim3(5376), 256, 0, stream>>>(x, xb, qkv_w, Wt1, proj_w, Wt2);
        gemm_bt<false, true><<<dim3(64, 18), 512, 0, stream>>>(
            xb, Wt1, qkv_b, qkO, VtO, 8192, 2304, 768, 1536);
        attn_kernel<<<dim3(96, 16), 256, 0, stream>>>(qkO, VtO, attnO);
        gemm_bt2<<<dim3(128, 6), 256, 0, stream>>>(
            attnO, Wt2, proj_b, out, 8192, 768, 768, 768);
    } else {
        // Per-batch path: ~13 MB workspace.
        transpose_f32_bf16<<<dim3(72, 24), 256, 0, stream>>>(qkv_w, Wt1, 768, 2304);
        transpose_f32_bf16<<<dim3(24, 24), 256, 0, stream>>>(proj_w, Wt2, 768, 768);
        ushort* xbB   = (ushort*)buf;
        ushort* qkB   = xbB + (size_t)1024 * 768;
        ushort* VtB   = qkB + (size_t)1024 * 1536;
        ushort* attnB = VtB + (size_t)1024 * 768;
        for (int b = 0; b < 8; b++) {
            const float* xp = x + (size_t)b * 1024 * 768;
            float* outb = out + (size_t)b * 1024 * 768;
            convert_f32_bf16<<<dim3(384), 256, 0, stream>>>(xp, xbB, 98304);
            gemm_bt<false, true><<<dim3(8, 18), 512, 0, stream>>>(
                xbB, Wt1, qkv_b, qkB, VtB, 1024, 2304, 768, 1536);
            attn_kernel<<<dim3(12, 16), 256, 0, stream>>>(qkB, VtB, attnB);
            gemm_bt2<<<dim3(16, 6), 256, 0, stream>>>(
                attnB, Wt2, proj_b, outb, 1024, 768, 768, 768);
        }
    }
}